// Round 14
// baseline (96.264 us; speedup 1.0000x reference)
//
#include <hip/hip_runtime.h>

// MechanicsPINN: residual = EI*biharm(f) + GC*lap(f) + KC*f - P,
// f = MLP(x) 2->256->512->1024->65536, B=64, grid 256x256. All inputs fp32.
// Round 14: R12 schedule (m201-style: global_load_lds, double-buffer,
// stage-before-wait, counted vmcnt, 2 raw barriers/step) scaled to 64-col
// tiles -> grid 1024 = 4 blocks/CU (R12 had 2). Phase-staggered blocks keep
// HBM busy through each other's compute phases. vmcnt(3) = 2 W + 1 A loads
// per thread per step. LDS 24KB/block.

#define BATCH 64
#define NPIX 65536

typedef __attribute__((ext_vector_type(8))) short short8_t;  // bf16 x8 (4 VGPR)
typedef __attribute__((ext_vector_type(4))) float f32x4;

__device__ __forceinline__ short f2bf(float x) {  // fp32 -> bf16 RNE
    unsigned u = __float_as_uint(x);
    unsigned r = (u + 0x7fffu + ((u >> 16) & 1u)) >> 16;
    return (short)r;
}

// -------- Fused layers 1+2: h2 = relu(relu(x@W1+b1) @ W2 + b2) --------
__global__ void k_layer12(const float* __restrict__ x, const float* __restrict__ W1,
                          const float* __restrict__ b1, const float* __restrict__ W2,
                          const float* __restrict__ b2, float* __restrict__ h2) {
    __shared__ float As[16][64];
    __shared__ float Ws[64][16];
    int tid = threadIdx.x;
    int tn = tid & 15, tm = tid >> 4;
    int n0 = blockIdx.x * 16, m0 = blockIdx.y * 16;
    float acc = 0.f;
    for (int k0 = 0; k0 < 256; k0 += 64) {
#pragma unroll
        for (int j = 0; j < 4; ++j) {          // build h1 16x64 tile on the fly
            int e = j * 256 + tid;
            int m = m0 + (e >> 6), kk = k0 + (e & 63);
            float v = x[m * 2 + 0] * W1[kk] + x[m * 2 + 1] * W1[256 + kk] + b1[kk];
            As[e >> 6][e & 63] = v > 0.f ? v : 0.f;
        }
#pragma unroll
        for (int j = 0; j < 4; ++j) {          // stage W2 64x16
            int e = j * 256 + tid;
            Ws[e >> 4][e & 15] = W2[(k0 + (e >> 4)) * 512 + n0 + (e & 15)];
        }
        __syncthreads();
#pragma unroll
        for (int k = 0; k < 64; ++k)
            acc += As[tm][k] * Ws[k][tn];
        __syncthreads();
    }
    acc += b2[n0 + tn];
    acc = acc > 0.f ? acc : 0.f;
    h2[(m0 + tm) * 512 + n0 + tn] = acc;
}

// -------- Layer 3: h3b(bf16) = relu(h2 @ W3 + b3), K=512, N=1024 --------
__global__ void k_layer3(const float* __restrict__ A, const float* __restrict__ Wt,
                         const float* __restrict__ bias, short* __restrict__ out_bf) {
    __shared__ float As[16][64];
    __shared__ float Ws[64][16];
    int tid = threadIdx.x;
    int tn = tid & 15, tm = tid >> 4;
    int n0 = blockIdx.x * 16, m0 = blockIdx.y * 16;
    float acc = 0.f;
    for (int k0 = 0; k0 < 512; k0 += 64) {
#pragma unroll
        for (int j = 0; j < 4; ++j) {
            int e = j * 256 + tid;
            As[e >> 6][e & 63] = A[(m0 + (e >> 6)) * 512 + k0 + (e & 63)];
        }
#pragma unroll
        for (int j = 0; j < 4; ++j) {
            int e = j * 256 + tid;
            Ws[e >> 4][e & 15] = Wt[(k0 + (e >> 4)) * 1024 + n0 + (e & 15)];
        }
        __syncthreads();
#pragma unroll
        for (int k = 0; k < 64; ++k)
            acc += As[tm][k] * Ws[k][tn];
        __syncthreads();
    }
    acc += bias[n0 + tn];
    acc = acc > 0.f ? acc : 0.f;
    out_bf[(m0 + tm) * 1024 + n0 + tn] = f2bf(acc);
}

// ---------- Main GEMM: f = h3b @ W4 + b4 (bf16 MFMA, M=64,N=65536,K=1024) ----
// 256 thr / 4 waves; block tile = 64 cols x 64 m; wave w owns cols
// w*16..w*16+15 (1 col-tile x 4 m-tiles = 4 MFMA per 32-k step).
// Double-buffered global_load_lds staging (2 W + 1 A loads/thread/step),
// stage-before-wait, inline vmcnt(3), two raw barriers per step.
__global__ __launch_bounds__(256) void k_gemm_mfma(
        const short* __restrict__ A,     // h3 bf16 [64][1024]
        const float* __restrict__ W,     // W4 fp32 [1024][65536]
        const float* __restrict__ bias,  // [65536]
        float* __restrict__ f) {         // [64][65536]
    __shared__ float Wt[2][32 * 64];     // 8 KB per buffer, [k][col^swz]
    __shared__ short At[2][4 * 64 * 8];  // 4 KB per buffer, [kq][m^swz][8]
    const int tid = threadIdx.x;
    const int w = tid >> 6;
    const int lane = tid & 63;
    const int lr = lane & 15;
    const int g = lane >> 4;             // k-group 0..3
    const int n0 = blockIdx.x * 64;

    f32x4 acc[4];                        // [m-tile]
#pragma unroll
    for (int a = 0; a < 4; ++a)
        acc[a] = {0.f, 0.f, 0.f, 0.f};

    // stage step s into buffer b: 2 W-chunks + 1 A-chunk per thread (16B each)
    auto stage = [&](int b, int s) {
#pragma unroll
        for (int i = 0; i < 2; ++i) {
            int c = i * 256 + tid;                 // 0..511
            int k = c >> 4;                        // 0..31
            int q4 = (c & 15) * 4;                 // float col offset 0..60
            int csw = q4 ^ (((k >> 3) & 1) << 4);  // source pre-swizzle (bit4)
            const float* src = W + (size_t)(s * 32 + k) * NPIX + n0 + csw;
            __builtin_amdgcn_global_load_lds(
                (const __attribute__((address_space(1))) void*)src,
                (__attribute__((address_space(3))) void*)((char*)&Wt[b][0] + c * 16),
                16, 0, 0);
        }
        {
            int kq = tid >> 6;                     // 0..3
            int ms = tid & 63;
            int md = ms ^ (kq << 2);               // source m pre-swizzle
            const short* asrc = A + md * 1024 + s * 32 + kq * 8;
            __builtin_amdgcn_global_load_lds(
                (const __attribute__((address_space(1))) void*)asrc,
                (__attribute__((address_space(3))) void*)((char*)&At[b][0] + tid * 16),
                16, 0, 0);
        }
    };

    stage(0, 0);

    for (int s = 0; s < 32; ++s) {
        const int cur = s & 1;
        if (s < 31) {
            stage(cur ^ 1, s + 1);                 // issue next step's loads
            asm volatile("s_waitcnt vmcnt(3)" ::: "memory");  // stage(s) landed
        } else {
            asm volatile("s_waitcnt vmcnt(0)" ::: "memory");
        }
        __builtin_amdgcn_sched_barrier(0);
        __builtin_amdgcn_s_barrier();    // everyone's stage(s) landed
        __builtin_amdgcn_sched_barrier(0);

        // A-frags: [kq=g][(mrow^(g<<2))]
        short8_t afr[4];
#pragma unroll
        for (int mt = 0; mt < 4; ++mt) {
            int mrow = mt * 16 + lr;
            afr[mt] = *(const short8_t*)((const short*)&At[cur][0] +
                                         g * 512 + (mrow ^ (g << 2)) * 8);
        }
        {
            const int col = w * 16 + lr;
            const int csw = col ^ ((g & 1) << 4);  // undo bit-4 swizzle
            short8_t bfr;
#pragma unroll
            for (int j = 0; j < 8; ++j)
                bfr[j] = f2bf(Wt[cur][(g * 8 + j) * 64 + csw]);
#pragma unroll
            for (int mt = 0; mt < 4; ++mt)
                acc[mt] = __builtin_amdgcn_mfma_f32_16x16x32_bf16(afr[mt], bfr, acc[mt], 0, 0, 0);
        }
        __builtin_amdgcn_s_barrier();    // reads of cur done before overwrite
    }

    // C/D layout: col = lane&15, row = (lane>>4)*4 + reg
    {
        const int col = n0 + w * 16 + lr;
        float bb = bias[col];
#pragma unroll
        for (int mt = 0; mt < 4; ++mt) {
            int rowb = mt * 16 + g * 4;
#pragma unroll
            for (int r = 0; r < 4; ++r)
                f[(size_t)(rowb + r) * NPIX + col] = acc[mt][r] + bb;
        }
    }
}

// --------------------------- Stencil ---------------------------
// residual = biharm + lap + f - P; reflect-1 index reflection.
#define ROWS 16
__device__ __forceinline__ int rfl(int i) {
    return i < 0 ? -i : (i > 255 ? 510 - i : i);
}
__global__ void k_stencil(const float* __restrict__ f, const float* __restrict__ P,
                          float* __restrict__ out) {
    __shared__ float fs[ROWS + 4][256];
    int x = threadIdx.x;
    int y0 = blockIdx.x * ROWS;
    int b = blockIdx.y;
    const float* fb = f + (size_t)b * NPIX;
    for (int t = 0; t < ROWS + 4; ++t) {
        int gy = rfl(y0 - 2 + t);
        fs[t][x] = fb[gy * 256 + x];
    }
    __syncthreads();

    int xm = x == 0 ? 1 : x - 1;
    int xp = x == 255 ? 254 : x + 1;

    auto lapAt = [&](int j, int i) {
        int s = j - y0 + 2;
        int sm = rfl(j - 1) - y0 + 2;
        int sp = rfl(j + 1) - y0 + 2;
        int im = i == 0 ? 1 : i - 1;
        int ip = i == 255 ? 254 : i + 1;
        float c = fs[s][i];
        return (fs[sm][i] - 2.f * c + fs[sp][i]) + (fs[s][im] - 2.f * c + fs[s][ip]);
    };

    for (int r = 0; r < ROWS; ++r) {
        int y = y0 + r;
        float lc = lapAt(y, x);
        float lym = lapAt(rfl(y - 1), x);
        float lyp = lapAt(rfl(y + 1), x);
        float lxm = lapAt(y, xm);
        float lxp = lapAt(y, xp);
        float bih = (lym - 2.f * lc + lyp) + (lxm - 2.f * lc + lxp);
        float fc = fs[r + 2][x];
        size_t idx = (size_t)b * NPIX + y * 256 + x;
        out[idx] = bih + lc + fc - P[idx];
    }
}

extern "C" void kernel_launch(void* const* d_in, const int* in_sizes, int n_in,
                              void* d_out, int out_size, void* d_ws, size_t ws_size,
                              hipStream_t stream) {
    const float* x  = (const float*)d_in[0];
    const float* P  = (const float*)d_in[1];
    const float* W1 = (const float*)d_in[2];
    const float* b1 = (const float*)d_in[3];
    const float* W2 = (const float*)d_in[4];
    const float* b2 = (const float*)d_in[5];
    const float* W3 = (const float*)d_in[6];
    const float* b3 = (const float*)d_in[7];
    const float* W4 = (const float*)d_in[8];
    const float* b4 = (const float*)d_in[9];
    float* out = (float*)d_out;

    char* ws = (char*)d_ws;
    float* h2  = (float*)(ws);                      // 64*512*4  = 128 KB
    short* h3b = (short*)(ws + (128 << 10));        // 64*1024*2 = 128 KB (bf16)
    float* f   = (float*)(ws + (256 << 10));        // 64*65536*4 = 16 MB

    k_layer12<<<dim3(512 / 16, 4), 256, 0, stream>>>(x, W1, b1, W2, b2, h2);
    k_layer3<<<dim3(1024 / 16, 4), 256, 0, stream>>>(h2, W3, b3, h3b);
    k_gemm_mfma<<<NPIX / 64, 256, 0, stream>>>(h3b, W4, b4, f);
    k_stencil<<<dim3(256 / ROWS, BATCH), 256, 0, stream>>>(f, P, out);
}

// Round 15
// 88.121 us; speedup vs baseline: 1.0924x; 1.0924x over previous
//
#include <hip/hip_runtime.h>

// MechanicsPINN: residual = EI*biharm(f) + GC*lap(f) + KC*f - P,
// f = MLP(x) 2->256->512->1024->65536, B=64, grid 256x256. All inputs fp32.
// Round 15: R12 GEMM + producer/consumer wave specialization.
// 512 thr: waves 0-3 = producers (global_load_lds + counted vmcnt only,
// DMA queue continuously fed), waves 4-7 = consumers (ds_read+f2bf+MFMA).
// Triple buffer, producers 1 step ahead, ONE s_barrier per step (all waves).
// Invariant at barrier k: stage(k) landed & consumers done with buf (k-1)%3;
// stage target (k+2)%3 disjoint from consumer read buf k%3 in every window.

#define BATCH 64
#define NPIX 65536

typedef __attribute__((ext_vector_type(8))) short short8_t;  // bf16 x8 (4 VGPR)
typedef __attribute__((ext_vector_type(4))) float f32x4;

__device__ __forceinline__ short f2bf(float x) {  // fp32 -> bf16 RNE
    unsigned u = __float_as_uint(x);
    unsigned r = (u + 0x7fffu + ((u >> 16) & 1u)) >> 16;
    return (short)r;
}

#define FULL_BARRIER() do { \
    __builtin_amdgcn_sched_barrier(0); \
    asm volatile("s_barrier" ::: "memory"); \
    __builtin_amdgcn_sched_barrier(0); } while (0)

// -------- Fused layers 1+2: h2 = relu(relu(x@W1+b1) @ W2 + b2) --------
__global__ void k_layer12(const float* __restrict__ x, const float* __restrict__ W1,
                          const float* __restrict__ b1, const float* __restrict__ W2,
                          const float* __restrict__ b2, float* __restrict__ h2) {
    __shared__ float As[16][64];
    __shared__ float Ws[64][16];
    int tid = threadIdx.x;
    int tn = tid & 15, tm = tid >> 4;
    int n0 = blockIdx.x * 16, m0 = blockIdx.y * 16;
    float acc = 0.f;
    for (int k0 = 0; k0 < 256; k0 += 64) {
#pragma unroll
        for (int j = 0; j < 4; ++j) {          // build h1 16x64 tile on the fly
            int e = j * 256 + tid;
            int m = m0 + (e >> 6), kk = k0 + (e & 63);
            float v = x[m * 2 + 0] * W1[kk] + x[m * 2 + 1] * W1[256 + kk] + b1[kk];
            As[e >> 6][e & 63] = v > 0.f ? v : 0.f;
        }
#pragma unroll
        for (int j = 0; j < 4; ++j) {          // stage W2 64x16
            int e = j * 256 + tid;
            Ws[e >> 4][e & 15] = W2[(k0 + (e >> 4)) * 512 + n0 + (e & 15)];
        }
        __syncthreads();
#pragma unroll
        for (int k = 0; k < 64; ++k)
            acc += As[tm][k] * Ws[k][tn];
        __syncthreads();
    }
    acc += b2[n0 + tn];
    acc = acc > 0.f ? acc : 0.f;
    h2[(m0 + tm) * 512 + n0 + tn] = acc;
}

// -------- Layer 3: h3b(bf16) = relu(h2 @ W3 + b3), K=512, N=1024 --------
__global__ void k_layer3(const float* __restrict__ A, const float* __restrict__ Wt,
                         const float* __restrict__ bias, short* __restrict__ out_bf) {
    __shared__ float As[16][64];
    __shared__ float Ws[64][16];
    int tid = threadIdx.x;
    int tn = tid & 15, tm = tid >> 4;
    int n0 = blockIdx.x * 16, m0 = blockIdx.y * 16;
    float acc = 0.f;
    for (int k0 = 0; k0 < 512; k0 += 64) {
#pragma unroll
        for (int j = 0; j < 4; ++j) {
            int e = j * 256 + tid;
            As[e >> 6][e & 63] = A[(m0 + (e >> 6)) * 512 + k0 + (e & 63)];
        }
#pragma unroll
        for (int j = 0; j < 4; ++j) {
            int e = j * 256 + tid;
            Ws[e >> 4][e & 15] = Wt[(k0 + (e >> 4)) * 1024 + n0 + (e & 15)];
        }
        __syncthreads();
#pragma unroll
        for (int k = 0; k < 64; ++k)
            acc += As[tm][k] * Ws[k][tn];
        __syncthreads();
    }
    acc += bias[n0 + tn];
    acc = acc > 0.f ? acc : 0.f;
    out_bf[(m0 + tm) * 1024 + n0 + tn] = f2bf(acc);
}

// ---------- Main GEMM: f = h3b @ W4 + b4 (bf16 MFMA, M=64,N=65536,K=1024) ----
// 512 thr / 8 waves; block tile = 128 cols x 64 m.
// Waves 0-3: producers (5 global_load_lds per thread per step).
// Waves 4-7: consumers; wave wc owns cols wc*32..+31 (2 col-tiles x 4 m-tiles
// = 8 MFMA per 32-k step). Triple-buffered; 1 barrier/step.
__global__ __launch_bounds__(512) void k_gemm_mfma(
        const short* __restrict__ A,     // h3 bf16 [64][1024]
        const float* __restrict__ W,     // W4 fp32 [1024][65536]
        const float* __restrict__ bias,  // [65536]
        float* __restrict__ f) {         // [64][65536]
    __shared__ float Wt[3][32 * 128];    // 16 KB per buffer, [k][col^swz]
    __shared__ short At[3][4 * 64 * 8];  // 4 KB per buffer, [kq][m^swz][8]
    const int tid = threadIdx.x;
    const int n0 = blockIdx.x * 128;
    const bool producer = tid < 256;

    // stage step s into buffer b: 4 W-chunks + 1 A-chunk per producer thread
    auto stage = [&](int b, int s) {
#pragma unroll
        for (int i = 0; i < 4; ++i) {
            int c = i * 256 + tid;                 // 0..1023
            int k = c >> 5;                        // 0..31
            int q4 = (c & 31) * 4;                 // float col-group
            int csw = q4 ^ (((k >> 3) & 1) << 4);  // source pre-swizzle (bit4)
            const float* src = W + (size_t)(s * 32 + k) * NPIX + n0 + csw;
            __builtin_amdgcn_global_load_lds(
                (const __attribute__((address_space(1))) void*)src,
                (__attribute__((address_space(3))) void*)((char*)&Wt[b][0] + c * 16),
                16, 0, 0);
        }
        {
            int kq = tid >> 6;                     // 0..3
            int ms = tid & 63;
            int md = ms ^ (kq << 2);               // source m pre-swizzle
            const short* asrc = A + md * 1024 + s * 32 + kq * 8;
            __builtin_amdgcn_global_load_lds(
                (const __attribute__((address_space(1))) void*)asrc,
                (__attribute__((address_space(3))) void*)((char*)&At[b][0] + tid * 16),
                16, 0, 0);
        }
    };

    if (producer) {
        stage(0, 0);
        stage(1, 1);
        asm volatile("s_waitcnt vmcnt(5)" ::: "memory");   // stage(0) landed
    }
    FULL_BARRIER();                       // barrier #0: stage(0) ready

    if (producer) {
        for (int s = 0; s < 32; ++s) {
            if (s + 2 < 32) stage((s + 2) % 3, s + 2);
            if (s < 30)
                asm volatile("s_waitcnt vmcnt(5)" ::: "memory");  // stage(s+1) landed
            else
                asm volatile("s_waitcnt vmcnt(0)" ::: "memory");
            FULL_BARRIER();               // barrier #s+1
        }
        return;                           // consumers do the epilogue
    }

    // ---- consumer path ----
    const int lane = tid & 63;
    const int w = (tid >> 6) - 4;        // 0..3
    const int lr = lane & 15;
    const int g = lane >> 4;             // k-group 0..3

    f32x4 acc[4][2];                     // [m-tile][col-tile]
#pragma unroll
    for (int a = 0; a < 4; ++a)
#pragma unroll
        for (int b = 0; b < 2; ++b)
            acc[a][b] = {0.f, 0.f, 0.f, 0.f};

    for (int s = 0; s < 32; ++s) {
        const int cur = s % 3;
        // A-frags: [kq=g][(mrow^(g<<2))]
        short8_t afr[4];
#pragma unroll
        for (int mt = 0; mt < 4; ++mt) {
            int mrow = mt * 16 + lr;
            afr[mt] = *(const short8_t*)((const short*)&At[cur][0] +
                                         g * 512 + (mrow ^ (g << 2)) * 8);
        }
#pragma unroll
        for (int t = 0; t < 2; ++t) {
            const int col = w * 32 + t * 16 + lr;
            const int csw = col ^ ((g & 1) << 4);  // undo bit-4 swizzle
            short8_t bfr;
#pragma unroll
            for (int j = 0; j < 8; ++j)
                bfr[j] = f2bf(Wt[cur][(g * 8 + j) * 128 + csw]);
#pragma unroll
            for (int mt = 0; mt < 4; ++mt)
                acc[mt][t] = __builtin_amdgcn_mfma_f32_16x16x32_bf16(afr[mt], bfr, acc[mt][t], 0, 0, 0);
        }
        FULL_BARRIER();                   // barrier #s+1 (matches producer)
    }

    // C/D layout: col = lane&15, row = (lane>>4)*4 + reg
#pragma unroll
    for (int t = 0; t < 2; ++t) {
        const int col = n0 + w * 32 + t * 16 + lr;
        float bb = bias[col];
#pragma unroll
        for (int mt = 0; mt < 4; ++mt) {
            int rowb = mt * 16 + g * 4;
#pragma unroll
            for (int r = 0; r < 4; ++r)
                f[(size_t)(rowb + r) * NPIX + col] = acc[mt][t][r] + bb;
        }
    }
}

// --------------------------- Stencil ---------------------------
// residual = biharm + lap + f - P; reflect-1 index reflection.
#define ROWS 16
__device__ __forceinline__ int rfl(int i) {
    return i < 0 ? -i : (i > 255 ? 510 - i : i);
}
__global__ void k_stencil(const float* __restrict__ f, const float* __restrict__ P,
                          float* __restrict__ out) {
    __shared__ float fs[ROWS + 4][256];
    int x = threadIdx.x;
    int y0 = blockIdx.x * ROWS;
    int b = blockIdx.y;
    const float* fb = f + (size_t)b * NPIX;
    for (int t = 0; t < ROWS + 4; ++t) {
        int gy = rfl(y0 - 2 + t);
        fs[t][x] = fb[gy * 256 + x];
    }
    __syncthreads();

    int xm = x == 0 ? 1 : x - 1;
    int xp = x == 255 ? 254 : x + 1;

    auto lapAt = [&](int j, int i) {
        int s = j - y0 + 2;
        int sm = rfl(j - 1) - y0 + 2;
        int sp = rfl(j + 1) - y0 + 2;
        int im = i == 0 ? 1 : i - 1;
        int ip = i == 255 ? 254 : i + 1;
        float c = fs[s][i];
        return (fs[sm][i] - 2.f * c + fs[sp][i]) + (fs[s][im] - 2.f * c + fs[s][ip]);
    };

    for (int r = 0; r < ROWS; ++r) {
        int y = y0 + r;
        float lc = lapAt(y, x);
        float lym = lapAt(rfl(y - 1), x);
        float lyp = lapAt(rfl(y + 1), x);
        float lxm = lapAt(y, xm);
        float lxp = lapAt(y, xp);
        float bih = (lym - 2.f * lc + lyp) + (lxm - 2.f * lc + lxp);
        float fc = fs[r + 2][x];
        size_t idx = (size_t)b * NPIX + y * 256 + x;
        out[idx] = bih + lc + fc - P[idx];
    }
}

extern "C" void kernel_launch(void* const* d_in, const int* in_sizes, int n_in,
                              void* d_out, int out_size, void* d_ws, size_t ws_size,
                              hipStream_t stream) {
    const float* x  = (const float*)d_in[0];
    const float* P  = (const float*)d_in[1];
    const float* W1 = (const float*)d_in[2];
    const float* b1 = (const float*)d_in[3];
    const float* W2 = (const float*)d_in[4];
    const float* b2 = (const float*)d_in[5];
    const float* W3 = (const float*)d_in[6];
    const float* b3 = (const float*)d_in[7];
    const float* W4 = (const float*)d_in[8];
    const float* b4 = (const float*)d_in[9];
    float* out = (float*)d_out;

    char* ws = (char*)d_ws;
    float* h2  = (float*)(ws);                      // 64*512*4  = 128 KB
    short* h3b = (short*)(ws + (128 << 10));        // 64*1024*2 = 128 KB (bf16)
    float* f   = (float*)(ws + (256 << 10));        // 64*65536*4 = 16 MB

    k_layer12<<<dim3(512 / 16, 4), 256, 0, stream>>>(x, W1, b1, W2, b2, h2);
    k_layer3<<<dim3(1024 / 16, 4), 256, 0, stream>>>(h2, W3, b3, h3b);
    k_gemm_mfma<<<NPIX / 128, 512, 0, stream>>>(h3b, W4, b4, f);
    k_stencil<<<dim3(256 / ROWS, BATCH), 256, 0, stream>>>(f, P, out);
}